// Round 2
// baseline (1831.196 us; speedup 1.0000x reference)
//
#include <hip/hip_runtime.h>

// IterativeGatedConv2D: 8 iterations of
//   g  = circ_depthwise_conv7x7(h, Wg)   (true convolution, kernel flipped)
//   ht = circ_depthwise_conv7x7(h, Wh)
//   h  = h + sigmoid(g) * (ht - h)
// Derivation: FFT with kernel placed at ((i-3)%H,(j-3)%W) == circular conv:
//   out[y,x,c] = sum_{i,j} K[c,i,j] * h[(y+3-i)%H, (x+3-j)%W, c]
//
// Layout: x is (B=8, H=256, W=256, C=64) channels-last fp32.
// Block: 256 threads = 64 channels (lane c = tid&63) x 4 x-positions (xi = tid>>6).
// Each thread computes TH=8 outputs along y. LDS tile (8+6)x(4+6)x64 fp32.
//
// R2: dropped __launch_bounds__(256,3) -> (256). R1's min-waves=3 forced
// VGPR_Count=84 < the ~125 live values (98 weights + 24 acc) => AGPR spill
// via v_accvgpr_read on every weight use (~2.3x VALU inst inflation,
// VALUBusy 45% with HBM at 15% = latency-bound on spill traffic).

#define HH 256
#define WW 256
#define CC 64
#define TH 8
#define TW 4
#define LH (TH + 6) // 14
#define LW (TW + 6) // 10

__global__ __launch_bounds__(256) void gated_step(
    const float* __restrict__ src,
    const float* __restrict__ wg_g,
    const float* __restrict__ wh_g,
    float* __restrict__ dst)
{
    __shared__ float tile[LH * LW * CC]; // 35840 B

    const int tid = threadIdx.x;
    const int c   = tid & 63;
    const int xi  = tid >> 6;      // 0..3
    const int x0  = blockIdx.x * TW;
    const int y0  = blockIdx.y * TH;
    const int b   = blockIdx.z;

    // ---- per-lane weights (channel c), 49 taps each, kept in registers ----
    float wg[49], wh[49];
    #pragma unroll
    for (int t = 0; t < 49; ++t) wg[t] = wg_g[c * 49 + t];
    #pragma unroll
    for (int t = 0; t < 49; ++t) wh[t] = wh_g[c * 49 + t];

    // ---- stage input tile with circular wrap, float4-vectorized ----
    // element sp = iy*LW + jx covers global (y0+iy-3, x0+jx-3); 16 float4 per sp.
    const float4* __restrict__ src4 = reinterpret_cast<const float4*>(src);
    const int total4 = LH * LW * (CC / 4); // 2240
    for (int k = tid; k < total4; k += 256) {
        int c4 = k & 15;
        int sp = k >> 4;              // 0..139
        int jx = sp % LW;
        int iy = sp / LW;
        int gy = (y0 + iy - 3) & 255;
        int gx = (x0 + jx - 3) & 255;
        float4 val = src4[(((b << 8) + gy) << 8 | gx) * (CC / 4) + c4];
        *reinterpret_cast<float4*>(&tile[(sp << 6) + (c4 << 2)]) = val;
    }
    __syncthreads();

    // ---- sliding-window compute: 8 outputs/thread along y ----
    float accg[TH], acch[TH], ctr[TH];
    #pragma unroll
    for (int r = 0; r < TH; ++r) { accg[r] = 0.0f; acch[r] = 0.0f; }

    #pragma unroll
    for (int iy = 0; iy < LH; ++iy) {
        float v[7];
        #pragma unroll
        for (int jv = 0; jv < 7; ++jv)
            v[jv] = tile[(iy * LW + xi + jv) * CC + c];
        if (iy >= 3 && iy < 3 + TH) ctr[iy - 3] = v[3]; // center tap = h itself
        #pragma unroll
        for (int r = 0; r < TH; ++r) {
            const int i = r + 6 - iy;   // kernel row index
            if (i >= 0 && i <= 6) {
                #pragma unroll
                for (int jv = 0; jv < 7; ++jv) {
                    // kernel col j = 6 - jv pairs with tap v[jv]
                    const float a = v[jv];
                    accg[r] = fmaf(wg[i * 7 + (6 - jv)], a, accg[r]);
                    acch[r] = fmaf(wh[i * 7 + (6 - jv)], a, acch[r]);
                }
            }
        }
    }

    // ---- epilogue: sigmoid gate + blend, coalesced store ----
    #pragma unroll
    for (int r = 0; r < TH; ++r) {
        float e = __expf(-accg[r]);
        float z = __builtin_amdgcn_rcpf(1.0f + e);
        float hn = fmaf(z, acch[r] - ctr[r], ctr[r]);
        int gy = y0 + r;
        int gx = x0 + xi;
        dst[((((b << 8) + gy) << 8) + gx) * CC + c] = hn;
    }
}

extern "C" void kernel_launch(void* const* d_in, const int* in_sizes, int n_in,
                              void* d_out, int out_size, void* d_ws, size_t ws_size,
                              hipStream_t stream) {
    const float* x  = (const float*)d_in[0];
    const float* wg = (const float*)d_in[1];
    const float* wh = (const float*)d_in[2];
    float* out = (float*)d_out;
    float* ws  = (float*)d_ws;

    dim3 grid(WW / TW, HH / TH, 8); // (64, 32, 8)
    dim3 block(256);

    // ping-pong: iter 0 -> ws, iter 1 -> out, ..., iter 7 -> out
    const float* src = x;
    for (int it = 0; it < 8; ++it) {
        float* dst = (it & 1) ? out : ws;
        gated_step<<<grid, block, 0, stream>>>(src, wg, wh, dst);
        src = dst;
    }
}

// Round 3
// 1826.230 us; speedup vs baseline: 1.0027x; 1.0027x over previous
//
#include <hip/hip_runtime.h>

// IterativeGatedConv2D: 8 iterations of
//   g  = circ_depthwise_conv7x7(h, Wg)   (true convolution, kernel flipped)
//   ht = circ_depthwise_conv7x7(h, Wh)
//   h  = h + sigmoid(g) * (ht - h)
// Derivation: FFT with kernel placed at ((i-3)%H,(j-3)%W) == circular conv:
//   out[y,x,c] = sum_{i,j} K[c,i,j] * h[(y+3-i)%H, (x+3-j)%W, c]
//
// Layout: x is (B=8, H=256, W=256, C=64) channels-last fp32.
// Block: 256 threads = 64 channels (lane c = tid&63) x 4 x-positions (xi = tid>>6).
// Each thread computes TH=8 outputs along y. LDS tile (8+6)x(4+6)x64 fp32.
//
// R3: __launch_bounds__(256, 1). History:
//  - R1 (256,3): VGPR capped at 84 < ~135 live (98 weights + acc) -> AGPR
//    spill movs, ~2190 VALU insts/wave vs ~950 real work, 260us/step.
//  - R2 (no launch_bounds): identical 84-VGPR codegen — default assumes
//    1024-thread workgroups + occupancy heuristic. No-op.
//  - R3 (256,1): flat wg=256, min 1 wave/EU -> allocator may use up to 512
//    VGPRs; ~135 live fits with zero spills. Occupancy ~2-3 blocks/CU is
//    fine: 16 independent FMA chains/thread give the ILP.

#define HH 256
#define WW 256
#define CC 64
#define TH 8
#define TW 4
#define LH (TH + 6) // 14
#define LW (TW + 6) // 10

__global__ __launch_bounds__(256, 1) void gated_step(
    const float* __restrict__ src,
    const float* __restrict__ wg_g,
    const float* __restrict__ wh_g,
    float* __restrict__ dst)
{
    __shared__ float tile[LH * LW * CC]; // 35840 B

    const int tid = threadIdx.x;
    const int c   = tid & 63;
    const int xi  = tid >> 6;      // 0..3
    const int x0  = blockIdx.x * TW;
    const int y0  = blockIdx.y * TH;
    const int b   = blockIdx.z;

    // ---- per-lane weights (channel c), 49 taps each, kept in registers ----
    float wg[49], wh[49];
    #pragma unroll
    for (int t = 0; t < 49; ++t) wg[t] = wg_g[c * 49 + t];
    #pragma unroll
    for (int t = 0; t < 49; ++t) wh[t] = wh_g[c * 49 + t];

    // ---- stage input tile with circular wrap, float4-vectorized ----
    // element sp = iy*LW + jx covers global (y0+iy-3, x0+jx-3); 16 float4 per sp.
    const float4* __restrict__ src4 = reinterpret_cast<const float4*>(src);
    const int total4 = LH * LW * (CC / 4); // 2240
    for (int k = tid; k < total4; k += 256) {
        int c4 = k & 15;
        int sp = k >> 4;              // 0..139
        int jx = sp % LW;
        int iy = sp / LW;
        int gy = (y0 + iy - 3) & 255;
        int gx = (x0 + jx - 3) & 255;
        float4 val = src4[(((b << 8) + gy) << 8 | gx) * (CC / 4) + c4];
        *reinterpret_cast<float4*>(&tile[(sp << 6) + (c4 << 2)]) = val;
    }
    __syncthreads();

    // ---- sliding-window compute: 8 outputs/thread along y ----
    float accg[TH], acch[TH], ctr[TH];
    #pragma unroll
    for (int r = 0; r < TH; ++r) { accg[r] = 0.0f; acch[r] = 0.0f; }

    #pragma unroll
    for (int iy = 0; iy < LH; ++iy) {
        float v[7];
        #pragma unroll
        for (int jv = 0; jv < 7; ++jv)
            v[jv] = tile[(iy * LW + xi + jv) * CC + c];
        if (iy >= 3 && iy < 3 + TH) ctr[iy - 3] = v[3]; // center tap = h itself
        #pragma unroll
        for (int r = 0; r < TH; ++r) {
            const int i = r + 6 - iy;   // kernel row index
            if (i >= 0 && i <= 6) {
                #pragma unroll
                for (int jv = 0; jv < 7; ++jv) {
                    // kernel col j = 6 - jv pairs with tap v[jv]
                    const float a = v[jv];
                    accg[r] = fmaf(wg[i * 7 + (6 - jv)], a, accg[r]);
                    acch[r] = fmaf(wh[i * 7 + (6 - jv)], a, acch[r]);
                }
            }
        }
    }

    // ---- epilogue: sigmoid gate + blend, coalesced store ----
    #pragma unroll
    for (int r = 0; r < TH; ++r) {
        float e = __expf(-accg[r]);
        float z = __builtin_amdgcn_rcpf(1.0f + e);
        float hn = fmaf(z, acch[r] - ctr[r], ctr[r]);
        int gy = y0 + r;
        int gx = x0 + xi;
        dst[((((b << 8) + gy) << 8) + gx) * CC + c] = hn;
    }
}

extern "C" void kernel_launch(void* const* d_in, const int* in_sizes, int n_in,
                              void* d_out, int out_size, void* d_ws, size_t ws_size,
                              hipStream_t stream) {
    const float* x  = (const float*)d_in[0];
    const float* wg = (const float*)d_in[1];
    const float* wh = (const float*)d_in[2];
    float* out = (float*)d_out;
    float* ws  = (float*)d_ws;

    dim3 grid(WW / TW, HH / TH, 8); // (64, 32, 8)
    dim3 block(256);

    // ping-pong: iter 0 -> ws, iter 1 -> out, ..., iter 7 -> out
    const float* src = x;
    for (int it = 0; it < 8; ++it) {
        float* dst = (it & 1) ? out : ws;
        gated_step<<<grid, block, 0, stream>>>(src, wg, wh, dst);
        src = dst;
    }
}